// Round 15
// baseline (85.344 us; speedup 1.0000x reference)
//
#include <hip/hip_runtime.h>

#define N_NODES 100000
#define N_EDGES 1600000
#define HIDDEN 256

#define BSH 7                    // bucket = dst >> 7
#define BNODES 128               // nodes per bucket
#define NB 782                   // ceil(100000 / 128)
#define NPB 256                  // place blocks == sub-chunks per bucket == consumer block size
#define EPB 6250                 // edges per place block (256*6250 = 1.6M exact)
#define SLOTS 32                 // slots per (bucket, pblock): mean 8, P(ovf)~4e-13/pair
#define NZT 391                  // z blocks: 256 threads = 256 nodes each, thread-per-node

// rec layout: [bucket][pblock][slot], 8B records {src(17b) | dstloc(7b)<<17, w}
// cnt layout: [bucket][pblock]  -> consumers read coalesced; fully overwritten each call

// ---- K1: place (blocks 0..255) + W12/cvec fold (block 256) ----
__global__ __launch_bounds__(1024) void k_place(
        const int* __restrict__ ei, const float* __restrict__ ew,
        const float* __restrict__ W1, const float* __restrict__ b1,
        const float* __restrict__ W2, const float* __restrict__ b2,
        int* __restrict__ cnt, uint2* __restrict__ rec,
        float* __restrict__ W12, float* __restrict__ cvec) {
    const int tid = threadIdx.x, bid = blockIdx.x;
    if (bid == NPB) {                                 // ---- fold block ----
        if (tid < HIDDEN) {
            const float4* w1r = (const float4*)(W1 + (size_t)tid * 128);
            float a0 = 0.f, a1 = 0.f;
#pragma unroll 8
            for (int k4 = 0; k4 < 32; ++k4) {
                float4 v = w1r[k4];
                a0 += v.x * W2[8 * k4 + 0]; a1 += v.x * W2[8 * k4 + 1];
                a0 += v.y * W2[8 * k4 + 2]; a1 += v.y * W2[8 * k4 + 3];
                a0 += v.z * W2[8 * k4 + 4]; a1 += v.z * W2[8 * k4 + 5];
                a0 += v.w * W2[8 * k4 + 6]; a1 += v.w * W2[8 * k4 + 7];
            }
            W12[2 * tid] = a0; W12[2 * tid + 1] = a1;
            if (tid < 2) {
                float acc = b2[tid];
                for (int k = 0; k < 128; ++k) acc += b1[k] * W2[2 * k + tid];
                cvec[tid] = acc;
            }
        }
        return;
    }
    __shared__ int cursor[NB];
    for (int i = tid; i < NB; i += 1024) cursor[i] = 0;
    __syncthreads();
    const int e0 = bid * EPB, e1 = e0 + EPB;
    for (int e = e0 + tid; e < e1; e += 1024) {
        int d = ei[N_EDGES + e];
        int s = ei[e];
        float wv = ew[e];
        int bk = ((unsigned)d) >> BSH;
        int pos = atomicAdd(&cursor[bk], 1);          // block-local LDS cursor
        if (pos < SLOTS)                              // ~4e-13 per pair
            rec[((size_t)bk * NPB + bid) * SLOTS + pos] =
                make_uint2((unsigned)s | ((unsigned)(d & (BNODES - 1)) << 17),
                           __float_as_uint(wv));
    }
    __syncthreads();
    for (int i = tid; i < NB; i += 1024)
        cnt[(size_t)i * NPB + bid] = min(cursor[i], SLOTS);   // covers ALL entries
}

// ---- K2: blocks 0..NZT-1: z = x@W12, ONE THREAD PER NODE (no cross-lane ops,
//          loads never drain). blocks NZT..NZT+NB-1: deg -> dinv. ----
__global__ __launch_bounds__(256) void k_zdeg(
        const float* __restrict__ x, const float* __restrict__ W12,
        const uint2* __restrict__ rec, const int* __restrict__ cnt,
        float* __restrict__ z, float* __restrict__ dinv) {
    __shared__ float lw0[HIDDEN], lw1[HIDDEN];
    __shared__ float acc[BNODES];
    const int tid = threadIdx.x, bid = blockIdx.x;
    if (bid < NZT) {
        // stage W12 into split LDS arrays (uniform-address reads = free broadcast)
        float2 wp = ((const float2*)W12)[tid];
        lw0[tid] = wp.x; lw1[tid] = wp.y;
        __syncthreads();
        const int node = bid * 256 + tid;
        if (node < N_NODES) {
            const float4* xp = (const float4*)(x + (size_t)node * HIDDEN);
            const float4* w0q = (const float4*)lw0;
            const float4* w1q = (const float4*)lw1;
            float a0 = 0.f, a1 = 0.f;
#pragma unroll 8
            for (int j = 0; j < 64; ++j) {            // 64 independent float4 loads
                float4 v = xp[j];
                float4 wa = w0q[j];
                float4 wb = w1q[j];
                a0 += v.x * wa.x + v.y * wa.y + v.z * wa.z + v.w * wa.w;
                a1 += v.x * wb.x + v.y * wb.y + v.z * wb.z + v.w * wb.w;
            }
            ((float2*)z)[node] = make_float2(a0, a1); // coalesced float2 store
        }
    } else {
        // ---------- deg for bucket, one thread per sub-chunk, paired loads ----------
        const int b = bid - NZT;
        if (tid < BNODES) acc[tid] = 1.0f;            // self-loop w=1
        __syncthreads();
        const int n = cnt[(size_t)b * NPB + tid];     // coalesced
        const uint2* r = rec + ((size_t)b * NPB + tid) * SLOTS;   // 256B-aligned
        int i = 0;
        for (; i + 2 <= n; i += 2) {
            uint4 q = *(const uint4*)(r + i);
            atomicAdd(&acc[q.x >> 17], __uint_as_float(q.y));
            atomicAdd(&acc[q.z >> 17], __uint_as_float(q.w));
        }
        if (i < n) {
            uint2 q = r[i];
            atomicAdd(&acc[q.x >> 17], __uint_as_float(q.y));
        }
        __syncthreads();
        if (tid < BNODES) {
            int node = b * BNODES + tid;
            if (node < N_NODES) dinv[node] = rsqrtf(acc[tid]);  // deg >= 1
        }
    }
}

// ---- K3: gather, one thread per sub-chunk, 2-wide unroll (4 gathers in flight);
//          flush fuses self-loop + bias ----
__global__ __launch_bounds__(256) void k_gather(
        const uint2* __restrict__ rec, const int* __restrict__ cnt,
        const float* __restrict__ dinv, const float* __restrict__ z,
        const float* __restrict__ cvec, float2* __restrict__ out) {
    __shared__ float ax[BNODES], ay[BNODES];
    const int tid = threadIdx.x, b = blockIdx.x;
    if (tid < BNODES) { ax[tid] = 0.f; ay[tid] = 0.f; }
    __syncthreads();
    const int n = cnt[(size_t)b * NPB + tid];             // coalesced
    const uint2* r = rec + ((size_t)b * NPB + tid) * SLOTS;
    int i = 0;
    for (; i + 2 <= n; i += 2) {
        uint4 q = *(const uint4*)(r + i);
        int s0 = (int)(q.x & 0x1FFFFu), s1 = (int)(q.z & 0x1FFFFu);
        float di0 = dinv[s0], di1 = dinv[s1];             // independent gathers
        float2 z0 = ((const float2*)z)[s0];
        float2 z1 = ((const float2*)z)[s1];
        float nw0 = di0 * __uint_as_float(q.y);
        float nw1 = di1 * __uint_as_float(q.w);
        int d0 = (int)(q.x >> 17), d1 = (int)(q.z >> 17);
        atomicAdd(&ax[d0], nw0 * z0.x);
        atomicAdd(&ay[d0], nw0 * z0.y);
        atomicAdd(&ax[d1], nw1 * z1.x);
        atomicAdd(&ay[d1], nw1 * z1.y);
    }
    if (i < n) {
        uint2 q = r[i];
        int s = (int)(q.x & 0x1FFFFu);
        float nw = dinv[s] * __uint_as_float(q.y);
        float2 zv = ((const float2*)z)[s];
        int dl = (int)(q.x >> 17);
        atomicAdd(&ax[dl], nw * zv.x);
        atomicAdd(&ay[dl], nw * zv.y);
    }
    __syncthreads();
    if (tid < BNODES) {
        int node = b * BNODES + tid;
        if (node < N_NODES) {
            float di = dinv[node];
            float2 zv = ((const float2*)z)[node];
            out[node] = make_float2(di * ax[tid] + di * di * zv.x + cvec[0],
                                    di * ay[tid] + di * di * zv.y + cvec[1]);
        }
    }
}

extern "C" void kernel_launch(void* const* d_in, const int* in_sizes, int n_in,
                              void* d_out, int out_size, void* d_ws, size_t ws_size,
                              hipStream_t stream) {
    const float* x  = (const float*)d_in[0];
    const int*   ei = (const int*)d_in[1];
    const float* ew = (const float*)d_in[2];
    const float* W1 = (const float*)d_in[3];
    const float* b1 = (const float*)d_in[4];
    const float* W2 = (const float*)d_in[5];
    const float* b2 = (const float*)d_in[6];
    float2* out = (float2*)d_out;

    char* ws = (char*)d_ws;
    uint2*  rec  = (uint2*)ws;           size_t off = (size_t)NB * NPB * SLOTS * 8;  // 51,249,152
    int*    cnt  = (int*)(ws + off);     off += (size_t)NB * NPB * 4;                // 800,768
    float*  dinv = (float*)(ws + off);   off += (size_t)N_NODES * 4;
    float*  z    = (float*)(ws + off);   off += (size_t)N_NODES * 8;
    float*  W12  = (float*)(ws + off);   off += HIDDEN * 2 * 4;
    float*  cvec = (float*)(ws + off);   off += 16;

    k_place <<<NPB + 1, 1024, 0, stream>>>(ei, ew, W1, b1, W2, b2, cnt, rec, W12, cvec);
    k_zdeg  <<<NZT + NB, 256, 0, stream>>>(x, W12, rec, cnt, z, dinv);
    k_gather<<<NB, 256, 0, stream>>>(rec, cnt, dinv, z, cvec, out);
}

// Round 16
// 80.058 us; speedup vs baseline: 1.0660x; 1.0660x over previous
//
#include <hip/hip_runtime.h>

#define N_NODES 100000
#define N_EDGES 1600000
#define HIDDEN 256

#define BSH 7                    // bucket = dst >> 7
#define BNODES 128               // nodes per bucket
#define NB 782                   // ceil(100000 / 128)
#define NPB 256                  // place blocks == sub-chunks per bucket == consumer block size
#define EPB 6250                 // edges per place block (256*6250 = 1.6M exact)
#define SLOTS 32                 // slots per (bucket, pblock): mean 8, P(ovf)~4e-13/pair
#define NZB 3125                 // z blocks: 4 waves x 8 nodes = 32 nodes/block, exact cover

typedef float f32x4 __attribute__((ext_vector_type(4)));

// rec layout: [bucket][pblock][slot], 8B records {src(17b) | dstloc(7b)<<17, w}
// cnt layout: [bucket][pblock]  -> consumers read coalesced; fully overwritten each call

// ---- K1: place (blocks 0..255) + W12/cvec fold (block 256) ----
__global__ __launch_bounds__(1024) void k_place(
        const int* __restrict__ ei, const float* __restrict__ ew,
        const float* __restrict__ W1, const float* __restrict__ b1,
        const float* __restrict__ W2, const float* __restrict__ b2,
        int* __restrict__ cnt, uint2* __restrict__ rec,
        float* __restrict__ W12, float* __restrict__ cvec) {
    const int tid = threadIdx.x, bid = blockIdx.x;
    if (bid == NPB) {                                 // ---- fold block ----
        if (tid < HIDDEN) {
            const float4* w1r = (const float4*)(W1 + (size_t)tid * 128);
            float a0 = 0.f, a1 = 0.f;
#pragma unroll 8
            for (int k4 = 0; k4 < 32; ++k4) {
                float4 v = w1r[k4];
                a0 += v.x * W2[8 * k4 + 0]; a1 += v.x * W2[8 * k4 + 1];
                a0 += v.y * W2[8 * k4 + 2]; a1 += v.y * W2[8 * k4 + 3];
                a0 += v.z * W2[8 * k4 + 4]; a1 += v.z * W2[8 * k4 + 5];
                a0 += v.w * W2[8 * k4 + 6]; a1 += v.w * W2[8 * k4 + 7];
            }
            W12[2 * tid] = a0; W12[2 * tid + 1] = a1;
            if (tid < 2) {
                float acc = b2[tid];
                for (int k = 0; k < 128; ++k) acc += b1[k] * W2[2 * k + tid];
                cvec[tid] = acc;
            }
        }
        return;
    }
    __shared__ int cursor[NB];
    for (int i = tid; i < NB; i += 1024) cursor[i] = 0;
    __syncthreads();
    const int e0 = bid * EPB, e1 = e0 + EPB;
    for (int e = e0 + tid; e < e1; e += 1024) {
        int d = ei[N_EDGES + e];
        int s = ei[e];
        float wv = ew[e];
        int bk = ((unsigned)d) >> BSH;
        int pos = atomicAdd(&cursor[bk], 1);          // block-local LDS cursor
        if (pos < SLOTS)                              // ~4e-13 per pair
            rec[((size_t)bk * NPB + bid) * SLOTS + pos] =
                make_uint2((unsigned)s | ((unsigned)(d & (BNODES - 1)) << 17),
                           __float_as_uint(wv));
    }
    __syncthreads();
    for (int i = tid; i < NB; i += 1024)
        cnt[(size_t)i * NPB + bid] = min(cursor[i], SLOTS);   // covers ALL entries
}

// ---- K2: blocks 0..NZB-1: z = x@W12, 8 rows (8KB/wave) issued via inline-asm
//          batch so the compiler cannot insert early waitcnts.
//          blocks NZB..NZB+NB-1: deg -> dinv. ----
__global__ __launch_bounds__(256) void k_zdeg(
        const float* __restrict__ x, const float* __restrict__ W12,
        const uint2* __restrict__ rec, const int* __restrict__ cnt,
        float* __restrict__ z, float* __restrict__ dinv) {
    __shared__ float acc[BNODES];
    const int tid = threadIdx.x, bid = blockIdx.x;
    if (bid < NZB) {
        const int lane = tid & 63;
        const float2 w0 = ((const float2*)W12)[lane * 4 + 0];
        const float2 w1 = ((const float2*)W12)[lane * 4 + 1];
        const float2 w2 = ((const float2*)W12)[lane * 4 + 2];
        const float2 w3 = ((const float2*)W12)[lane * 4 + 3];
        const int n0 = (bid * 4 + (tid >> 6)) * 8;    // 8 nodes/wave, 3125*32=100000
        const float* p = x + (size_t)n0 * HIDDEN + lane * 4;
        f32x4 v0, v1, v2, v3, v4, v5, v6, v7;
        // ---- 8 KB of loads issued back-to-back; compiler can't split them ----
        asm volatile("global_load_dwordx4 %0, %1, off" : "=v"(v0) : "v"(p));
        asm volatile("global_load_dwordx4 %0, %1, off" : "=v"(v1) : "v"(p + 1 * HIDDEN));
        asm volatile("global_load_dwordx4 %0, %1, off" : "=v"(v2) : "v"(p + 2 * HIDDEN));
        asm volatile("global_load_dwordx4 %0, %1, off" : "=v"(v3) : "v"(p + 3 * HIDDEN));
        asm volatile("global_load_dwordx4 %0, %1, off" : "=v"(v4) : "v"(p + 4 * HIDDEN));
        asm volatile("global_load_dwordx4 %0, %1, off" : "=v"(v5) : "v"(p + 5 * HIDDEN));
        asm volatile("global_load_dwordx4 %0, %1, off" : "=v"(v6) : "v"(p + 6 * HIDDEN));
        asm volatile("global_load_dwordx4 %0, %1, off" : "=v"(v7) : "v"(p + 7 * HIDDEN));
        // ---- single drain; "+v" operands make every consumer depend on it ----
        asm volatile("s_waitcnt vmcnt(0)"
                     : "+v"(v0), "+v"(v1), "+v"(v2), "+v"(v3),
                       "+v"(v4), "+v"(v5), "+v"(v6), "+v"(v7));
        float a0 = v0.x*w0.x + v0.y*w1.x + v0.z*w2.x + v0.w*w3.x;
        float b0 = v0.x*w0.y + v0.y*w1.y + v0.z*w2.y + v0.w*w3.y;
        float a1 = v1.x*w0.x + v1.y*w1.x + v1.z*w2.x + v1.w*w3.x;
        float b1 = v1.x*w0.y + v1.y*w1.y + v1.z*w2.y + v1.w*w3.y;
        float a2 = v2.x*w0.x + v2.y*w1.x + v2.z*w2.x + v2.w*w3.x;
        float b2 = v2.x*w0.y + v2.y*w1.y + v2.z*w2.y + v2.w*w3.y;
        float a3 = v3.x*w0.x + v3.y*w1.x + v3.z*w2.x + v3.w*w3.x;
        float b3 = v3.x*w0.y + v3.y*w1.y + v3.z*w2.y + v3.w*w3.y;
        float a4 = v4.x*w0.x + v4.y*w1.x + v4.z*w2.x + v4.w*w3.x;
        float b4 = v4.x*w0.y + v4.y*w1.y + v4.z*w2.y + v4.w*w3.y;
        float a5 = v5.x*w0.x + v5.y*w1.x + v5.z*w2.x + v5.w*w3.x;
        float b5 = v5.x*w0.y + v5.y*w1.y + v5.z*w2.y + v5.w*w3.y;
        float a6 = v6.x*w0.x + v6.y*w1.x + v6.z*w2.x + v6.w*w3.x;
        float b6 = v6.x*w0.y + v6.y*w1.y + v6.z*w2.y + v6.w*w3.y;
        float a7 = v7.x*w0.x + v7.y*w1.x + v7.z*w2.x + v7.w*w3.x;
        float b7 = v7.x*w0.y + v7.y*w1.y + v7.z*w2.y + v7.w*w3.y;
#pragma unroll
        for (int m = 1; m <= 32; m <<= 1) {
            a0 += __shfl_xor(a0, m, 64);  b0 += __shfl_xor(b0, m, 64);
            a1 += __shfl_xor(a1, m, 64);  b1 += __shfl_xor(b1, m, 64);
            a2 += __shfl_xor(a2, m, 64);  b2 += __shfl_xor(b2, m, 64);
            a3 += __shfl_xor(a3, m, 64);  b3 += __shfl_xor(b3, m, 64);
            a4 += __shfl_xor(a4, m, 64);  b4 += __shfl_xor(b4, m, 64);
            a5 += __shfl_xor(a5, m, 64);  b5 += __shfl_xor(b5, m, 64);
            a6 += __shfl_xor(a6, m, 64);  b6 += __shfl_xor(b6, m, 64);
            a7 += __shfl_xor(a7, m, 64);  b7 += __shfl_xor(b7, m, 64);
        }
        if (lane == 0) {
            *(float4*)(z + 2 * n0 + 0)  = make_float4(a0, b0, a1, b1);
            *(float4*)(z + 2 * n0 + 4)  = make_float4(a2, b2, a3, b3);
            *(float4*)(z + 2 * n0 + 8)  = make_float4(a4, b4, a5, b5);
            *(float4*)(z + 2 * n0 + 12) = make_float4(a6, b6, a7, b7);
        }
    } else {
        // ---------- deg for bucket, one thread per sub-chunk, paired loads ----------
        const int b = bid - NZB;
        if (tid < BNODES) acc[tid] = 1.0f;            // self-loop w=1
        __syncthreads();
        const int n = cnt[(size_t)b * NPB + tid];     // coalesced
        const uint2* r = rec + ((size_t)b * NPB + tid) * SLOTS;   // 256B-aligned
        int i = 0;
        for (; i + 2 <= n; i += 2) {
            uint4 q = *(const uint4*)(r + i);
            atomicAdd(&acc[q.x >> 17], __uint_as_float(q.y));
            atomicAdd(&acc[q.z >> 17], __uint_as_float(q.w));
        }
        if (i < n) {
            uint2 q = r[i];
            atomicAdd(&acc[q.x >> 17], __uint_as_float(q.y));
        }
        __syncthreads();
        if (tid < BNODES) {
            int node = b * BNODES + tid;
            if (node < N_NODES) dinv[node] = rsqrtf(acc[tid]);  // deg >= 1
        }
    }
}

// ---- K3: gather, one thread per sub-chunk, 2-wide unroll (4 gathers in flight);
//          flush fuses self-loop + bias ----
__global__ __launch_bounds__(256) void k_gather(
        const uint2* __restrict__ rec, const int* __restrict__ cnt,
        const float* __restrict__ dinv, const float* __restrict__ z,
        const float* __restrict__ cvec, float2* __restrict__ out) {
    __shared__ float ax[BNODES], ay[BNODES];
    const int tid = threadIdx.x, b = blockIdx.x;
    if (tid < BNODES) { ax[tid] = 0.f; ay[tid] = 0.f; }
    __syncthreads();
    const int n = cnt[(size_t)b * NPB + tid];             // coalesced
    const uint2* r = rec + ((size_t)b * NPB + tid) * SLOTS;
    int i = 0;
    for (; i + 2 <= n; i += 2) {
        uint4 q = *(const uint4*)(r + i);
        int s0 = (int)(q.x & 0x1FFFFu), s1 = (int)(q.z & 0x1FFFFu);
        float di0 = dinv[s0], di1 = dinv[s1];             // independent gathers
        float2 z0 = ((const float2*)z)[s0];
        float2 z1 = ((const float2*)z)[s1];
        float nw0 = di0 * __uint_as_float(q.y);
        float nw1 = di1 * __uint_as_float(q.w);
        int d0 = (int)(q.x >> 17), d1 = (int)(q.z >> 17);
        atomicAdd(&ax[d0], nw0 * z0.x);
        atomicAdd(&ay[d0], nw0 * z0.y);
        atomicAdd(&ax[d1], nw1 * z1.x);
        atomicAdd(&ay[d1], nw1 * z1.y);
    }
    if (i < n) {
        uint2 q = r[i];
        int s = (int)(q.x & 0x1FFFFu);
        float nw = dinv[s] * __uint_as_float(q.y);
        float2 zv = ((const float2*)z)[s];
        int dl = (int)(q.x >> 17);
        atomicAdd(&ax[dl], nw * zv.x);
        atomicAdd(&ay[dl], nw * zv.y);
    }
    __syncthreads();
    if (tid < BNODES) {
        int node = b * BNODES + tid;
        if (node < N_NODES) {
            float di = dinv[node];
            float2 zv = ((const float2*)z)[node];
            out[node] = make_float2(di * ax[tid] + di * di * zv.x + cvec[0],
                                    di * ay[tid] + di * di * zv.y + cvec[1]);
        }
    }
}

extern "C" void kernel_launch(void* const* d_in, const int* in_sizes, int n_in,
                              void* d_out, int out_size, void* d_ws, size_t ws_size,
                              hipStream_t stream) {
    const float* x  = (const float*)d_in[0];
    const int*   ei = (const int*)d_in[1];
    const float* ew = (const float*)d_in[2];
    const float* W1 = (const float*)d_in[3];
    const float* b1 = (const float*)d_in[4];
    const float* W2 = (const float*)d_in[5];
    const float* b2 = (const float*)d_in[6];
    float2* out = (float2*)d_out;

    char* ws = (char*)d_ws;
    uint2*  rec  = (uint2*)ws;           size_t off = (size_t)NB * NPB * SLOTS * 8;  // 51,249,152
    int*    cnt  = (int*)(ws + off);     off += (size_t)NB * NPB * 4;                // 800,768
    float*  dinv = (float*)(ws + off);   off += (size_t)N_NODES * 4;
    float*  z    = (float*)(ws + off);   off += (size_t)N_NODES * 8;
    float*  W12  = (float*)(ws + off);   off += HIDDEN * 2 * 4;
    float*  cvec = (float*)(ws + off);   off += 16;

    k_place <<<NPB + 1, 1024, 0, stream>>>(ei, ew, W1, b1, W2, b2, cnt, rec, W12, cvec);
    k_zdeg  <<<NZB + NB, 256, 0, stream>>>(x, W12, rec, cnt, z, dinv);
    k_gather<<<NB, 256, 0, stream>>>(rec, cnt, dinv, z, cvec, out);
}

// Round 17
// 78.816 us; speedup vs baseline: 1.0828x; 1.0158x over previous
//
#include <hip/hip_runtime.h>

#define N_NODES 100000
#define N_EDGES 1600000
#define HIDDEN 256

#define BSH 7                    // bucket = dst >> 7
#define BNODES 128               // nodes per bucket
#define NB 782                   // ceil(100000 / 128)
#define NPB 256                  // place blocks == sub-chunks per bucket == consumer block size
#define EPB 6250                 // edges per place block (256*6250 = 1.6M exact)
#define SLOTS 32                 // slots per (bucket, pblock): mean 8, P(ovf)~4e-13/pair
#define NZB 3125                 // z blocks: 4 waves x 8 nodes = 32 nodes/block, exact cover

// rec layout: [bucket][pblock][slot], 8B records {src(17b) | dstloc(7b)<<17, w}
// cnt layout: [bucket][pblock]  -> consumers read coalesced; fully overwritten each call
// W12 layout: SPLIT — W12[0..255] = col0, W12[256..511] = col1

// ---- K1: place (blocks 0..255) + W12/cvec fold (block 256) ----
__global__ __launch_bounds__(1024) void k_place(
        const int* __restrict__ ei, const float* __restrict__ ew,
        const float* __restrict__ W1, const float* __restrict__ b1,
        const float* __restrict__ W2, const float* __restrict__ b2,
        int* __restrict__ cnt, uint2* __restrict__ rec,
        float* __restrict__ W12, float* __restrict__ cvec) {
    const int tid = threadIdx.x, bid = blockIdx.x;
    if (bid == NPB) {                                 // ---- fold block ----
        if (tid < HIDDEN) {
            const float4* w1r = (const float4*)(W1 + (size_t)tid * 128);
            float a0 = 0.f, a1 = 0.f;
#pragma unroll 8
            for (int k4 = 0; k4 < 32; ++k4) {
                float4 v = w1r[k4];
                a0 += v.x * W2[8 * k4 + 0]; a1 += v.x * W2[8 * k4 + 1];
                a0 += v.y * W2[8 * k4 + 2]; a1 += v.y * W2[8 * k4 + 3];
                a0 += v.z * W2[8 * k4 + 4]; a1 += v.z * W2[8 * k4 + 5];
                a0 += v.w * W2[8 * k4 + 6]; a1 += v.w * W2[8 * k4 + 7];
            }
            W12[tid] = a0;                            // split layout: col0
            W12[HIDDEN + tid] = a1;                   // col1
            if (tid < 2) {
                float acc = b2[tid];
                for (int k = 0; k < 128; ++k) acc += b1[k] * W2[2 * k + tid];
                cvec[tid] = acc;
            }
        }
        return;
    }
    __shared__ int cursor[NB];
    for (int i = tid; i < NB; i += 1024) cursor[i] = 0;
    __syncthreads();
    const int e0 = bid * EPB, e1 = e0 + EPB;
    for (int e = e0 + tid; e < e1; e += 1024) {
        int d = ei[N_EDGES + e];
        int s = ei[e];
        float wv = ew[e];
        int bk = ((unsigned)d) >> BSH;
        int pos = atomicAdd(&cursor[bk], 1);          // block-local LDS cursor
        if (pos < SLOTS)                              // ~4e-13 per pair
            rec[((size_t)bk * NPB + bid) * SLOTS + pos] =
                make_uint2((unsigned)s | ((unsigned)(d & (BNODES - 1)) << 17),
                           __float_as_uint(wv));
    }
    __syncthreads();
    for (int i = tid; i < NB; i += 1024)
        cnt[(size_t)i * NPB + bid] = min(cursor[i], SLOTS);   // covers ALL entries
}

// ---- K2: blocks 0..NZB-1: z = x@W12 via global_load_lds staging (no dest VGPR,
//          compiler cannot serialize the stream). blocks NZB..: deg -> dinv. ----
__global__ __launch_bounds__(256) void k_zdeg(
        const float* __restrict__ x, const float* __restrict__ W12,
        const uint2* __restrict__ rec, const int* __restrict__ cnt,
        float* __restrict__ z, float* __restrict__ dinv) {
    __shared__ float tile[4][8][HIDDEN];              // 32 KB: [wave][row][feat]
    __shared__ float acc[BNODES];
    const int tid = threadIdx.x, bid = blockIdx.x;
    if (bid < NZB) {
        const int wv   = tid >> 6;
        const int lane = tid & 63;
        const int sub  = lane & 7;                    // feature-quad group
        const int nl   = lane >> 3;                   // node within wave's 8
        // weights for feature-quads {sub + 8j}: 16 float4 regs (L2-resident)
        float4 wa[8], wb[8];
#pragma unroll
        for (int j = 0; j < 8; ++j) {
            wa[j] = *(const float4*)(W12 + (sub + 8 * j) * 4);
            wb[j] = *(const float4*)(W12 + HIDDEN + (sub + 8 * j) * 4);
        }
        const int rowbase = bid * 32 + wv * 8;        // this wave's 8 nodes
        // ---- stage 8 rows (8 KB) via LDS-direct loads: no VGPR dests ----
#pragma unroll
        for (int j = 0; j < 8; ++j) {
            const float* gsrc = x + (size_t)(rowbase + j) * HIDDEN + lane * 4;
            __builtin_amdgcn_global_load_lds(
                (const __attribute__((address_space(1))) void*)gsrc,
                (__attribute__((address_space(3))) void*)&tile[wv][j][0],
                16, 0, 0);
        }
        asm volatile("s_waitcnt vmcnt(0)" ::: "memory");
        // ---- compute from LDS: bank-balanced strided float4 reads ----
        float a0 = 0.f, a1 = 0.f;
#pragma unroll
        for (int j = 0; j < 8; ++j) {
            float4 v = *(const float4*)&tile[wv][nl][(sub + 8 * j) * 4];
            a0 += v.x * wa[j].x + v.y * wa[j].y + v.z * wa[j].z + v.w * wa[j].w;
            a1 += v.x * wb[j].x + v.y * wb[j].y + v.z * wb[j].z + v.w * wb[j].w;
        }
#pragma unroll
        for (int m = 1; m <= 4; m <<= 1) {            // reduce across 8 subs
            a0 += __shfl_xor(a0, m, 64);
            a1 += __shfl_xor(a1, m, 64);
        }
        if (sub == 0) ((float2*)z)[rowbase + nl] = make_float2(a0, a1);
    } else {
        // ---------- deg for bucket, one thread per sub-chunk, paired loads ----------
        const int b = bid - NZB;
        if (tid < BNODES) acc[tid] = 1.0f;            // self-loop w=1
        __syncthreads();
        const int n = cnt[(size_t)b * NPB + tid];     // coalesced
        const uint2* r = rec + ((size_t)b * NPB + tid) * SLOTS;   // 256B-aligned
        int i = 0;
        for (; i + 2 <= n; i += 2) {
            uint4 q = *(const uint4*)(r + i);
            atomicAdd(&acc[q.x >> 17], __uint_as_float(q.y));
            atomicAdd(&acc[q.z >> 17], __uint_as_float(q.w));
        }
        if (i < n) {
            uint2 q = r[i];
            atomicAdd(&acc[q.x >> 17], __uint_as_float(q.y));
        }
        __syncthreads();
        if (tid < BNODES) {
            int node = b * BNODES + tid;
            if (node < N_NODES) dinv[node] = rsqrtf(acc[tid]);  // deg >= 1
        }
    }
}

// ---- K3: gather, one thread per sub-chunk, 2-wide unroll (4 gathers in flight);
//          flush fuses self-loop + bias ----
__global__ __launch_bounds__(256) void k_gather(
        const uint2* __restrict__ rec, const int* __restrict__ cnt,
        const float* __restrict__ dinv, const float* __restrict__ z,
        const float* __restrict__ cvec, float2* __restrict__ out) {
    __shared__ float ax[BNODES], ay[BNODES];
    const int tid = threadIdx.x, b = blockIdx.x;
    if (tid < BNODES) { ax[tid] = 0.f; ay[tid] = 0.f; }
    __syncthreads();
    const int n = cnt[(size_t)b * NPB + tid];             // coalesced
    const uint2* r = rec + ((size_t)b * NPB + tid) * SLOTS;
    int i = 0;
    for (; i + 2 <= n; i += 2) {
        uint4 q = *(const uint4*)(r + i);
        int s0 = (int)(q.x & 0x1FFFFu), s1 = (int)(q.z & 0x1FFFFu);
        float di0 = dinv[s0], di1 = dinv[s1];             // independent gathers
        float2 z0 = ((const float2*)z)[s0];
        float2 z1 = ((const float2*)z)[s1];
        float nw0 = di0 * __uint_as_float(q.y);
        float nw1 = di1 * __uint_as_float(q.w);
        int d0 = (int)(q.x >> 17), d1 = (int)(q.z >> 17);
        atomicAdd(&ax[d0], nw0 * z0.x);
        atomicAdd(&ay[d0], nw0 * z0.y);
        atomicAdd(&ax[d1], nw1 * z1.x);
        atomicAdd(&ay[d1], nw1 * z1.y);
    }
    if (i < n) {
        uint2 q = r[i];
        int s = (int)(q.x & 0x1FFFFu);
        float nw = dinv[s] * __uint_as_float(q.y);
        float2 zv = ((const float2*)z)[s];
        int dl = (int)(q.x >> 17);
        atomicAdd(&ax[dl], nw * zv.x);
        atomicAdd(&ay[dl], nw * zv.y);
    }
    __syncthreads();
    if (tid < BNODES) {
        int node = b * BNODES + tid;
        if (node < N_NODES) {
            float di = dinv[node];
            float2 zv = ((const float2*)z)[node];
            out[node] = make_float2(di * ax[tid] + di * di * zv.x + cvec[0],
                                    di * ay[tid] + di * di * zv.y + cvec[1]);
        }
    }
}

extern "C" void kernel_launch(void* const* d_in, const int* in_sizes, int n_in,
                              void* d_out, int out_size, void* d_ws, size_t ws_size,
                              hipStream_t stream) {
    const float* x  = (const float*)d_in[0];
    const int*   ei = (const int*)d_in[1];
    const float* ew = (const float*)d_in[2];
    const float* W1 = (const float*)d_in[3];
    const float* b1 = (const float*)d_in[4];
    const float* W2 = (const float*)d_in[5];
    const float* b2 = (const float*)d_in[6];
    float2* out = (float2*)d_out;

    char* ws = (char*)d_ws;
    uint2*  rec  = (uint2*)ws;           size_t off = (size_t)NB * NPB * SLOTS * 8;  // 51,249,152
    int*    cnt  = (int*)(ws + off);     off += (size_t)NB * NPB * 4;                // 800,768
    float*  dinv = (float*)(ws + off);   off += (size_t)N_NODES * 4;
    float*  z    = (float*)(ws + off);   off += (size_t)N_NODES * 8;
    float*  W12  = (float*)(ws + off);   off += HIDDEN * 2 * 4;
    float*  cvec = (float*)(ws + off);   off += 16;

    k_place <<<NPB + 1, 1024, 0, stream>>>(ei, ew, W1, b1, W2, b2, cnt, rec, W12, cvec);
    k_zdeg  <<<NZB + NB, 256, 0, stream>>>(x, W12, rec, cnt, z, dinv);
    k_gather<<<NB, 256, 0, stream>>>(rec, cnt, dinv, z, cvec, out);
}